// Round 12
// baseline (45.441 us; speedup 1.0000x reference)
//
#include <hip/hip_runtime.h>
#include <hip/hip_bf16.h>
#include <math.h>

typedef __attribute__((ext_vector_type(8))) short short8;
typedef __attribute__((ext_vector_type(4))) float f32x4;
typedef __attribute__((ext_vector_type(2))) float f32x2;

namespace {
constexpr int BS    = 4;
constexpr int LSZ   = 256;
constexpr int CROPD = 246;
constexpr int NPTS  = BS * LSZ * LSZ;      // 262144
constexpr int NCROP = BS * CROPD * CROPD;  // 242064

constexpr int SZ_OMSI   = BS * 4 * CROPD * CROPD;
constexpr int SZ_OOFF   = BS * CROPD * CROPD * 2;
constexpr int SZ_PREMSI = BS * CROPD * CROPD;
constexpr int SZ_PREPAN = BS * CROPD * CROPD;
constexpr int SZ_OFFSET = NPTS * 2;
constexpr int SZ_SPEKC  = BS * CROPD * CROPD * 5;

constexpr int OFF_OMSI   = 0;
constexpr int OFF_OOFF   = OFF_OMSI + SZ_OMSI;
constexpr int OFF_PREMSI = OFF_OOFF + SZ_OOFF;
constexpr int OFF_PREPAN = OFF_PREMSI + SZ_PREMSI;
constexpr int OFF_OFFSET = OFF_PREPAN + SZ_PREPAN;
constexpr int OFF_SPEKC  = OFF_OFFSET + SZ_OFFSET;
constexpr int OFF_SPAK   = OFF_SPEKC + SZ_SPEKC;

// d_ws dword layout (prep_kernel output):
constexpr int WS_W2F   = 0;     // 7168 dw : w2 B-fragments (bf16 pairs)
constexpr int WS_HBF   = 7168;  //  512 dw : head B-fragments (bf16 pairs)
constexpr int WS_W1P   = 7680;  //  224 dw : (w1a,w1b) bf16 pairs, [kt][q][8]
constexpr int WS_B1T   = 7904;  //  224 dw : b1 f32, [kt][q][8]
constexpr int WS_B2V   = 8128;  //   64 dw : b2 padded to [4][16] f32
constexpr int WS_HBIAS = 8192;  //   16 dw : head biases per out-slot
constexpr int WS_NDW   = 8208;
} // namespace

static __device__ __forceinline__ unsigned short bf16u(float x) {
    __hip_bfloat16 h = __float2bfloat16(x);
    return __builtin_bit_cast(unsigned short, h);
}
static __device__ __forceinline__ unsigned int pk2(float a, float b) {
    return (unsigned int)bf16u(a) | ((unsigned int)bf16u(b) << 16);
}
// HW packed f32->bf16 (RNE), 1 instr vs ~11 software. [T12 recipe]
static __device__ __forceinline__ unsigned int cvtpk(float lo, float hi) {
    unsigned int r;
    asm("v_cvt_pk_bf16_f32 %0, %1, %2" : "=v"(r) : "v"(lo), "v"(hi));
    return r;
}
static __device__ __forceinline__ f32x2 pkfma(f32x2 a, f32x2 b, f32x2 c) {
    return __builtin_elementwise_fma(a, b, c);
}

// ---------------- prep: pack all weights into d_ws (runs every call) -------
__global__ __launch_bounds__(256) void prep_kernel(
    const float* __restrict__ w1, const float* __restrict__ b1,
    const float* __restrict__ w2, const float* __restrict__ b2,
    const float* __restrict__ wo, const float* __restrict__ bo,
    const float* __restrict__ wse, const float* __restrict__ bse,
    const float* __restrict__ wsa, const float* __restrict__ bsa,
    unsigned int* __restrict__ ws)
{
    const int d = blockIdx.x * 256 + threadIdx.x;
    if (d < 7168) {                       // W2F
        const int pi = d >> 8, rem = d & 255, lane = rem >> 2, jj = rem & 3;
        const int kt = pi >> 2, nt = pi & 3, q = lane >> 4, m = lane & 15;
        const int r0 = kt * 32 + q * 8 + 2 * jj, col = nt * 16 + m;
        const float v0 = (col < 50 && r0     < 200) ? w2[r0 * 50 + col]       : 0.f;
        const float v1 = (col < 50 && r0 + 1 < 200) ? w2[(r0 + 1) * 50 + col] : 0.f;
        ws[d] = pk2(v0, v1);
    } else if (d < 7680) {                // HBF
        const int e = d - 7168;
        const int kt2 = e >> 8, rem = e & 255, lane = rem >> 2, jj = rem & 3;
        const int q = lane >> 4, m = lane & 15;
        float v[2];
#pragma unroll
        for (int hlf = 0; hlf < 2; ++hlf) {
            const int f = kt2 * 32 + q * 8 + 2 * jj + hlf;
            float val = 0.f;
            if (f < 50 && m < 11) {
                if      (m < 2) val = wo [f * 2 + m];
                else if (m < 7) val = wse[f * 5 + (m - 2)];
                else            val = wsa[f * 4 + (m - 7)];
            }
            v[hlf] = val;
        }
        ws[d] = pk2(v[0], v[1]);
    } else if (d < 7904) {                // W1P
        const int e = d - 7680;
        const int kt = e >> 5, q = (e >> 3) & 3, j = e & 7;
        const int k = kt * 32 + q * 8 + j;
        const float a = (k < 200) ? w1[k]       : 0.f;
        const float b = (k < 200) ? w1[200 + k] : 0.f;
        ws[d] = pk2(a, b);
    } else if (d < 8128) {                // B1T (f32)
        const int e = d - 7904;
        const int kt = e >> 5, q = (e >> 3) & 3, j = e & 7;
        const int k = kt * 32 + q * 8 + j;
        ws[d] = __float_as_uint((k < 200) ? b1[k] : 0.f);
    } else if (d < 8192) {                // B2V
        const int e = d - 8128;
        const int f = (e >> 4) * 16 + (e & 15);
        ws[d] = __float_as_uint((f < 50) ? b2[f] : 0.f);
    } else if (d < WS_NDW) {              // HBIAS
        const int m = d - 8192;
        const float v = (m < 2) ? bo[m] : (m < 7) ? bse[m - 2] : (m < 11) ? bsa[m - 7] : 0.f;
        ws[d] = __float_as_uint(v);
    }
}

// ---------------- MLP kernel: T=2 tiles/wave, 24 waves/CU ------------------
// R12: occupancy attack. R11's T=4 fused kernel was reg-capped (64 VGPR +
// 64 acc-AGPR ~= 128/512 pool -> 4 waves/SIMD) and LDS-capped (4 blk/CU).
// T=2 drops acc to 32 AGPR (~85 total regs = 6 waves/SIMD cap); 512-thread
// blocks share the 28672B w2f stage; LDS 47104B -> 3 blocks/CU = 24 waves.
// bc un-fused: it runs at full occupancy standalone (R8: ~5us).
__global__ __launch_bounds__(512, 6) void mlp_kernel(
    const float* __restrict__ coords,
    const unsigned int* __restrict__ ws,
    float* __restrict__ out)
{
    __shared__ __align__(16) unsigned int   s_w2f[7168];        // 28672 B
    __shared__ __align__(16) unsigned short s_f2[8][16 * 72];   // 18432 B

    const int tid  = threadIdx.x;
    const int lane = tid & 63;
    const int wv   = tid >> 6;        // 0..7
    const int q    = lane >> 4;
    const int m    = lane & 15;
    const float* wsf = reinterpret_cast<const float*>(ws);

    const int pb0 = (blockIdx.x * 8 + wv) * 32;   // 1024 blocks, 32 pts/wave

    const float2 cA = reinterpret_cast<const float2*>(coords)[pb0 + m];
    const float2 cB = reinterpret_cast<const float2*>(coords)[pb0 + 16 + m];

    // stage W2F into LDS (1792 uint4)
    {
        const uint4* __restrict__ g4 = reinterpret_cast<const uint4*>(ws);
        uint4* __restrict__ s4 = reinterpret_cast<uint4*>(s_w2f);
#pragma unroll 1
        for (int i = 0; i < 4; ++i) {
            const int idx = tid + i * 512;
            if (idx < 1792) s4[idx] = g4[idx];
        }
    }
    __syncthreads();

    // ---- layer 1 (packed f32x2, HW cvt) + main GEMM, ROLLED kt loop ----
    f32x4 acc0[4] = {{0,0,0,0},{0,0,0,0},{0,0,0,0},{0,0,0,0}};
    f32x4 acc1[4] = {{0,0,0,0},{0,0,0,0},{0,0,0,0},{0,0,0,0}};

#pragma unroll 1
    for (int kt = 0; kt < 7; ++kt) {
        const uint4 u0 = *reinterpret_cast<const uint4*>(ws + WS_W1P + kt * 32 + q * 8);
        const uint4 u1 = *reinterpret_cast<const uint4*>(ws + WS_W1P + kt * 32 + q * 8 + 4);
        const float4 bb0 = *reinterpret_cast<const float4*>(wsf + WS_B1T + kt * 32 + q * 8);
        const float4 bb1 = *reinterpret_cast<const float4*>(wsf + WS_B1T + kt * 32 + q * 8 + 4);
        const unsigned int uu[8] = {u0.x, u0.y, u0.z, u0.w, u1.x, u1.y, u1.z, u1.w};
        const float bbf[8] = {bb0.x, bb0.y, bb0.z, bb0.w, bb1.x, bb1.y, bb1.z, bb1.w};

        union { unsigned int u[4]; short8 s; } a0, a1;
#pragma unroll
        for (int jp = 0; jp < 4; ++jp) {
            const f32x2 wa = {__uint_as_float(uu[2 * jp] << 16),
                              __uint_as_float(uu[2 * jp + 1] << 16)};
            const f32x2 wb = {__uint_as_float(uu[2 * jp] & 0xffff0000u),
                              __uint_as_float(uu[2 * jp + 1] & 0xffff0000u)};
            const f32x2 bv = {bbf[2 * jp], bbf[2 * jp + 1]};
            f32x2 hA = pkfma((f32x2){cA.x, cA.x}, wa, pkfma((f32x2){cA.y, cA.y}, wb, bv));
            f32x2 hB = pkfma((f32x2){cB.x, cB.x}, wa, pkfma((f32x2){cB.y, cB.y}, wb, bv));
            hA = __builtin_elementwise_max(hA, (f32x2){0.f, 0.f});
            hB = __builtin_elementwise_max(hB, (f32x2){0.f, 0.f});
            a0.u[jp] = cvtpk(hA[0], hA[1]);
            a1.u[jp] = cvtpk(hB[0], hB[1]);
        }
#pragma unroll
        for (int nt = 0; nt < 4; ++nt) {
            const short8 Bf = *reinterpret_cast<const short8*>(&s_w2f[((kt * 4 + nt) * 64 + lane) * 4]);
            acc0[nt] = __builtin_amdgcn_mfma_f32_16x16x32_bf16(a0.s, Bf, acc0[nt], 0, 0, 0);
            acc1[nt] = __builtin_amdgcn_mfma_f32_16x16x32_bf16(a1.s, Bf, acc1[nt], 0, 0, 0);
        }
    }

    // ---- heads (HW cvt pairs; per-wave f2 LDS; compiler-scheduled waits) --
    const float hbias = wsf[WS_HBIAS + m];
    float b2v[4];
#pragma unroll
    for (int nt = 0; nt < 4; ++nt) b2v[nt] = wsf[WS_B2V + nt * 16 + m];
    const short8 hB0 = *reinterpret_cast<const short8*>(ws + WS_HBF + lane * 4);
    const short8 hB1 = *reinterpret_cast<const short8*>(ws + WS_HBF + 256 + lane * 4);

    unsigned short* f2b = s_f2[wv];

#pragma unroll
    for (int t = 0; t < 2; ++t) {
        const f32x4* acc = t ? acc1 : acc0;
#pragma unroll
        for (int nt = 0; nt < 4; ++nt) {
#pragma unroll
            for (int rp = 0; rp < 2; ++rp) {
                const float v0 = fmaxf(acc[nt][2 * rp]     + b2v[nt], 0.f);
                const float v1 = fmaxf(acc[nt][2 * rp + 1] + b2v[nt], 0.f);
                const unsigned int u = cvtpk(v0, v1);
                f2b[(q * 4 + 2 * rp)     * 72 + nt * 16 + m] = (unsigned short)u;
                f2b[(q * 4 + 2 * rp + 1) * 72 + nt * 16 + m] = (unsigned short)(u >> 16);
            }
        }

        const short8 Af0 = *reinterpret_cast<const short8*>(&f2b[m * 72 +  0 + q * 8]);
        const short8 Af1 = *reinterpret_cast<const short8*>(&f2b[m * 72 + 32 + q * 8]);
        f32x4 h4 = {0, 0, 0, 0};
        h4 = __builtin_amdgcn_mfma_f32_16x16x32_bf16(Af0, hB0, h4, 0, 0, 0);
        h4 = __builtin_amdgcn_mfma_f32_16x16x32_bf16(Af1, hB1, h4, 0, 0, 0);

        const int pbase = pb0 + t * 16;
#pragma unroll
        for (int r = 0; r < 4; ++r) {
            const float v = h4[r] + hbias;
            const int n = pbase + q * 4 + r;
            if (m < 2) {
                out[OFF_OFFSET + 2 * n + m] = v;
            } else if (m < 7) {
                const int b = n >> 16;
                const int h = (n >> 8) & 255;
                const int w = n & 255;
                if (h >= 5 && h < 251 && w >= 5 && w < 251)
                    out[OFF_SPEKC + (((b * CROPD) + (h - 5)) * CROPD + (w - 5)) * 5 + (m - 2)] = v;
            } else if (m < 11) {
                out[OFF_SPAK + 4 * n + (m - 7)] = v;
            }
        }
    }
}

// ---------------- bc kernel: conv + grid-sample (zero LDS, 1 pt/thread) ----
__global__ __launch_bounds__(256) void bc_kernel(
    const float* __restrict__ pan,
    const float* __restrict__ msi,
    float* __restrict__ out)
{
    const int t = blockIdx.x * blockDim.x + threadIdx.x;
    if (t >= NCROP) return;

    const int b  = t / (CROPD * CROPD);
    const int r  = t % (CROPD * CROPD);
    const int hh = r / CROPD;
    const int ww = r % CROPD;
    const int h = hh + 5, w = ww + 5;
    const int n = (b << 16) + (h << 8) + w;

    const float off0 = out[OFF_OFFSET + 2 * n + 0];
    const float off1 = out[OFF_OFFSET + 2 * n + 1];
    out[OFF_OOFF + 2 * t + 0] = off0;
    out[OFF_OOFF + 2 * t + 1] = off1;

    const float* spak = out + OFF_SPAK;
    const float a = spak[4 * n + 0];
    const float c = spak[4 * n + 2];
    const float d = spak[4 * n + 3];
    const float inv00 = a * a + c * c;
    const float inv01 = c * d;
    const float inv11 = d * d;

    // grid-sample setup (gathers issued early)
    const float gx = fmaf((float)w, 2.0f / 255.0f, -1.0f) + off0 * (1.0f / 128.0f);
    const float gy = fmaf((float)h, 2.0f / 255.0f, -1.0f) + off1 * (1.0f / 128.0f);
    const float px = (gx + 1.0f) * 0.5f * 255.0f;
    const float py = (gy + 1.0f) * 0.5f * 255.0f;
    const float x0f = floorf(px), y0f = floorf(py);
    const float wx1 = px - x0f,  wy1 = py - y0f;
    const int x0 = (int)x0f, y0 = (int)y0f;
    const int x1 = x0 + 1,  y1 = y0 + 1;
    const bool vx0 = (x0 >= 0) & (x0 < 256);
    const bool vx1 = (x1 >= 0) & (x1 < 256);
    const bool vy0 = (y0 >= 0) & (y0 < 256);
    const bool vy1 = (y1 >= 0) & (y1 < 256);
    const int cx0 = min(max(x0, 0), 255), cx1 = min(max(x1, 0), 255);
    const int cy0 = min(max(y0, 0), 255), cy1 = min(max(y1, 0), 255);
    const float w00 = (1.0f - wy1) * (1.0f - wx1) * (float)(vy0 & vx0);
    const float w01 = (1.0f - wy1) * wx1          * (float)(vy0 & vx1);
    const float w10 = wy1 * (1.0f - wx1)          * (float)(vy1 & vx0);
    const float w11 = wy1 * wx1                   * (float)(vy1 & vx1);
    const int i00 = cy0 * 256 + cx0;
    const int i01 = cy0 * 256 + cx1;
    const int i10 = cy1 * 256 + cx0;
    const int i11 = cy1 * 256 + cx1;
    const float* mb = msi + ((size_t)b * 4) * 65536;
    float m00[4], m01[4], m10[4], m11[4];
#pragma unroll
    for (int ch = 0; ch < 4; ++ch) {
        const float* mc = mb + ch * 65536;
        m00[ch] = mc[i00]; m01[ch] = mc[i01]; m10[ch] = mc[i10]; m11[ch] = mc[i11];
    }

    // spatially-variant conv, central symmetry kv(p,q)=kv(14-p,14-q);
    // exp2-space quadratic, forward differencing; bare v_exp_f32.
    const float c00 = -0.72134752f * inv00;   // -0.5*log2(e)*inv00
    const float c01 = -1.44269504f * inv01;   // -log2(e)*inv01
    const float c11 = -0.72134752f * inv11;
    const float* prow = pan + ((size_t)b << 20) + (size_t)(4 * h - 6) * 1024 + (4 * w - 6);

    float ksum = 1.0f;
    float conv = prow[7 * 1024 + 7];
    {
        float arg = c11;
        float dk  = 3.0f * c11;
#pragma unroll
        for (int k = 1; k <= 7; ++k) {
            const float kv = __builtin_amdgcn_exp2f(arg);
            ksum += 2.0f * kv;
            conv = fmaf(kv, prow[7 * 1024 + 7 - k] + prow[7 * 1024 + 7 + k], conv);
            arg += dk; dk += 2.0f * c11;
        }
    }
#pragma unroll 1
    for (int p = 0; p < 7; ++p) {            // rows p & 14-p
        const float gp = (float)(p - 7);
        const float cg = c01 * gp;
        float arg = fmaf(cg, -7.0f, fmaf(c00 * gp, gp, 49.0f * c11));
        float dq  = fmaf(-13.0f, c11, cg);
        const float dd = 2.0f * c11;
        const float* pa = prow + p * 1024;
        const float* pc = prow + (14 - p) * 1024;
#pragma unroll
        for (int qq = 0; qq < 15; ++qq) {
            const float kv = __builtin_amdgcn_exp2f(arg);
            ksum += 2.0f * kv;
            conv = fmaf(kv, pa[qq] + pc[14 - qq], conv);
            arg += dq; dq += dd;
        }
    }
    out[OFF_PREPAN + t] = conv / ksum;

    // finish sample + pre_msi
    const float* spc = out + OFF_SPEKC + 5 * t;
    float pm = spc[4];
#pragma unroll
    for (int ch = 0; ch < 4; ++ch) {
        const float v = w00 * m00[ch] + w01 * m01[ch] + w10 * m10[ch] + w11 * m11[ch];
        out[OFF_OMSI + (((b * 4) + ch) * CROPD + hh) * CROPD + ww] = v;
        pm = fmaf(v, spc[ch], pm);
    }
    out[OFF_PREMSI + t] = pm;
}

extern "C" void kernel_launch(void* const* d_in, const int* in_sizes, int n_in,
                              void* d_out, int out_size, void* d_ws, size_t ws_size,
                              hipStream_t stream)
{
    const float* msi    = (const float*)d_in[0];
    const float* pan    = (const float*)d_in[1];
    const float* coords = (const float*)d_in[2];
    const float* w1  = (const float*)d_in[3];
    const float* b1  = (const float*)d_in[4];
    const float* w2  = (const float*)d_in[5];
    const float* b2  = (const float*)d_in[6];
    const float* wo  = (const float*)d_in[7];
    const float* bo  = (const float*)d_in[8];
    const float* wse = (const float*)d_in[9];
    const float* bse = (const float*)d_in[10];
    const float* wsa = (const float*)d_in[11];
    const float* bsa = (const float*)d_in[12];
    float* out = (float*)d_out;
    unsigned int* ws = (unsigned int*)d_ws;

    prep_kernel<<<(WS_NDW + 255) / 256, 256, 0, stream>>>(
        w1, b1, w2, b2, wo, bo, wse, bse, wsa, bsa, ws);
    mlp_kernel<<<1024, 512, 0, stream>>>(coords, ws, out);
    const int gcrop = (NCROP + 255) / 256;
    bc_kernel<<<gcrop, 256, 0, stream>>>(pan, msi, out);
}

// Round 13
// 35.885 us; speedup vs baseline: 1.2663x; 1.2663x over previous
//
#include <hip/hip_runtime.h>
#include <hip/hip_bf16.h>
#include <math.h>

typedef __attribute__((ext_vector_type(8))) short short8;
typedef __attribute__((ext_vector_type(4))) float f32x4;
typedef __attribute__((ext_vector_type(2))) float f32x2;

namespace {
constexpr int BS    = 4;
constexpr int LSZ   = 256;
constexpr int CROPD = 246;
constexpr int NPTS  = BS * LSZ * LSZ;      // 262144
constexpr int NCROP = BS * CROPD * CROPD;  // 242064

constexpr int SZ_OMSI   = BS * 4 * CROPD * CROPD;
constexpr int SZ_OOFF   = BS * CROPD * CROPD * 2;
constexpr int SZ_PREMSI = BS * CROPD * CROPD;
constexpr int SZ_PREPAN = BS * CROPD * CROPD;
constexpr int SZ_OFFSET = NPTS * 2;
constexpr int SZ_SPEKC  = BS * CROPD * CROPD * 5;

constexpr int OFF_OMSI   = 0;
constexpr int OFF_OOFF   = OFF_OMSI + SZ_OMSI;
constexpr int OFF_PREMSI = OFF_OOFF + SZ_OOFF;
constexpr int OFF_PREPAN = OFF_PREMSI + SZ_PREMSI;
constexpr int OFF_OFFSET = OFF_PREPAN + SZ_PREPAN;
constexpr int OFF_SPEKC  = OFF_OFFSET + SZ_OFFSET;
constexpr int OFF_SPAK   = OFF_SPEKC + SZ_SPEKC;

// d_ws dword layout (prep_kernel output):
constexpr int WS_W2F   = 0;     // 7168 dw : w2 B-fragments (bf16 pairs)
constexpr int WS_HBF   = 7168;  //  512 dw : head B-fragments (bf16 pairs)
constexpr int WS_W1P   = 7680;  //  224 dw : (w1a,w1b) bf16 pairs, [kt][q][8]
constexpr int WS_B1T   = 7904;  //  224 dw : b1 f32, [kt][q][8]
constexpr int WS_B2V   = 8128;  //   64 dw : b2 padded to [4][16] f32
constexpr int WS_HBIAS = 8192;  //   16 dw : head biases per out-slot
constexpr int WS_NDW   = 8208;

constexpr int FS = 20;          // f2 feature-row stride in ushorts (40 B, 8B-aligned)
} // namespace

static __device__ __forceinline__ unsigned short bf16u(float x) {
    __hip_bfloat16 h = __float2bfloat16(x);
    return __builtin_bit_cast(unsigned short, h);
}
static __device__ __forceinline__ unsigned int pk2(float a, float b) {
    return (unsigned int)bf16u(a) | ((unsigned int)bf16u(b) << 16);
}
// HW packed f32->bf16 (RNE), 1 instr. [T12 recipe]
static __device__ __forceinline__ unsigned int cvtpk(float lo, float hi) {
    unsigned int r;
    asm("v_cvt_pk_bf16_f32 %0, %1, %2" : "=v"(r) : "v"(lo), "v"(hi));
    return r;
}
static __device__ __forceinline__ f32x2 pkfma(f32x2 a, f32x2 b, f32x2 c) {
    return __builtin_elementwise_fma(a, b, c);
}

// ---------------- prep: pack all weights into d_ws (runs every call) -------
__global__ __launch_bounds__(256) void prep_kernel(
    const float* __restrict__ w1, const float* __restrict__ b1,
    const float* __restrict__ w2, const float* __restrict__ b2,
    const float* __restrict__ wo, const float* __restrict__ bo,
    const float* __restrict__ wse, const float* __restrict__ bse,
    const float* __restrict__ wsa, const float* __restrict__ bsa,
    unsigned int* __restrict__ ws)
{
    const int d = blockIdx.x * 256 + threadIdx.x;
    if (d < 7168) {                       // W2F
        const int pi = d >> 8, rem = d & 255, lane = rem >> 2, jj = rem & 3;
        const int kt = pi >> 2, nt = pi & 3, q = lane >> 4, m = lane & 15;
        const int r0 = kt * 32 + q * 8 + 2 * jj, col = nt * 16 + m;
        const float v0 = (col < 50 && r0     < 200) ? w2[r0 * 50 + col]       : 0.f;
        const float v1 = (col < 50 && r0 + 1 < 200) ? w2[(r0 + 1) * 50 + col] : 0.f;
        ws[d] = pk2(v0, v1);
    } else if (d < 7680) {                // HBF
        const int e = d - 7168;
        const int kt2 = e >> 8, rem = e & 255, lane = rem >> 2, jj = rem & 3;
        const int q = lane >> 4, m = lane & 15;
        float v[2];
#pragma unroll
        for (int hlf = 0; hlf < 2; ++hlf) {
            const int f = kt2 * 32 + q * 8 + 2 * jj + hlf;
            float val = 0.f;
            if (f < 50 && m < 11) {
                if      (m < 2) val = wo [f * 2 + m];
                else if (m < 7) val = wse[f * 5 + (m - 2)];
                else            val = wsa[f * 4 + (m - 7)];
            }
            v[hlf] = val;
        }
        ws[d] = pk2(v[0], v[1]);
    } else if (d < 7904) {                // W1P
        const int e = d - 7680;
        const int kt = e >> 5, q = (e >> 3) & 3, j = e & 7;
        const int k = kt * 32 + q * 8 + j;
        const float a = (k < 200) ? w1[k]       : 0.f;
        const float b = (k < 200) ? w1[200 + k] : 0.f;
        ws[d] = pk2(a, b);
    } else if (d < 8128) {                // B1T (f32)
        const int e = d - 7904;
        const int kt = e >> 5, q = (e >> 3) & 3, j = e & 7;
        const int k = kt * 32 + q * 8 + j;
        ws[d] = __float_as_uint((k < 200) ? b1[k] : 0.f);
    } else if (d < 8192) {                // B2V
        const int e = d - 8128;
        const int f = (e >> 4) * 16 + (e & 15);
        ws[d] = __float_as_uint((f < 50) ? b2[f] : 0.f);
    } else if (d < WS_NDW) {              // HBIAS
        const int m = d - 8192;
        const float v = (m < 2) ? bo[m] : (m < 7) ? bse[m - 2] : (m < 11) ? bsa[m - 7] : 0.f;
        ws[d] = __float_as_uint(v);
    }
}

// ---------------- fused: MLP (MFMA) + conv + grid-sample -------------------
// R13 = R11 base (best config: T=4 fused, rolled kt, HW cvt_pk, bare v_exp,
// 39936B LDS -> 4 blk/CU) + two shared-pipe diets (R12 showed shared-pipe
// throughput, not occupancy, binds):
//  (a) feature-major f2 tile [feature][point], stride 20 ushorts:
//      transpose write = 4x ds_write_b64/tile (was 64x ds_write_b16);
//      A-frag read = 16x ds_read_u16/tile at <=2-way bank alias.
//  (b) all MLP output stores moved to bc phase via xfer: float2 offset +
//      float4 spak + 5-float spek, coalesced, no divergent scatter.
__global__ __launch_bounds__(256, 4) void fused_kernel(
    const float* __restrict__ coords,
    const unsigned int* __restrict__ ws,
    const float* __restrict__ pan,
    const float* __restrict__ msi,
    float* __restrict__ out)
{
    __shared__ __align__(16) unsigned int  s_w2f[7168];      // 28672 B
    __shared__ __align__(16) unsigned char s_buf[4][2816];   // 11264 B
    // per-wave s_buf: phase1 = f2T [64 feat][20] ushort (2560B); phase2 = xfer 64x11 f32

    const int tid  = threadIdx.x;
    const int lane = tid & 63;
    const int wv   = tid >> 6;
    const int q    = lane >> 4;
    const int m    = lane & 15;
    const float* wsf = reinterpret_cast<const float*>(ws);

    const int pb0 = (blockIdx.x * 4 + wv) * 64;   // 1024 blocks, 64 pts/wave

    float2 cc[4];
#pragma unroll
    for (int t = 0; t < 4; ++t)
        cc[t] = reinterpret_cast<const float2*>(coords)[pb0 + t * 16 + m];

    // stage W2F into LDS (1792 uint4, exact)
    {
        const uint4* __restrict__ g4 = reinterpret_cast<const uint4*>(ws);
        uint4* __restrict__ s4 = reinterpret_cast<uint4*>(s_w2f);
#pragma unroll 1
        for (int i = 0; i < 7; ++i) s4[tid + i * 256] = g4[tid + i * 256];
    }
    __syncthreads();

    // ---- layer 1 (packed f32x2, HW cvt) + main GEMM, ROLLED kt loop ----
    f32x4 acc[4][4];
#pragma unroll
    for (int t = 0; t < 4; ++t)
#pragma unroll
        for (int nt = 0; nt < 4; ++nt) acc[t][nt] = (f32x4){0, 0, 0, 0};

#pragma unroll 1
    for (int kt = 0; kt < 7; ++kt) {
        const uint4 u0 = *reinterpret_cast<const uint4*>(ws + WS_W1P + kt * 32 + q * 8);
        const uint4 u1 = *reinterpret_cast<const uint4*>(ws + WS_W1P + kt * 32 + q * 8 + 4);
        const float4 bb0 = *reinterpret_cast<const float4*>(wsf + WS_B1T + kt * 32 + q * 8);
        const float4 bb1 = *reinterpret_cast<const float4*>(wsf + WS_B1T + kt * 32 + q * 8 + 4);
        const unsigned int uu[8] = {u0.x, u0.y, u0.z, u0.w, u1.x, u1.y, u1.z, u1.w};
        const float bbf[8] = {bb0.x, bb0.y, bb0.z, bb0.w, bb1.x, bb1.y, bb1.z, bb1.w};

        f32x2 wa[4], wb[4], bv[4];
#pragma unroll
        for (int jp = 0; jp < 4; ++jp) {
            wa[jp] = (f32x2){__uint_as_float(uu[2 * jp] << 16),
                             __uint_as_float(uu[2 * jp + 1] << 16)};
            wb[jp] = (f32x2){__uint_as_float(uu[2 * jp] & 0xffff0000u),
                             __uint_as_float(uu[2 * jp + 1] & 0xffff0000u)};
            bv[jp] = (f32x2){bbf[2 * jp], bbf[2 * jp + 1]};
        }

        short8 A[4];
#pragma unroll
        for (int t = 0; t < 4; ++t) {
            const f32x2 cx = {cc[t].x, cc[t].x};
            const f32x2 cy = {cc[t].y, cc[t].y};
            union { unsigned int u[4]; short8 s; } af;
#pragma unroll
            for (int jp = 0; jp < 4; ++jp) {
                f32x2 h = pkfma(cx, wa[jp], pkfma(cy, wb[jp], bv[jp]));
                h = __builtin_elementwise_max(h, (f32x2){0.f, 0.f});
                af.u[jp] = cvtpk(h[0], h[1]);
            }
            A[t] = af.s;
        }
#pragma unroll
        for (int nt = 0; nt < 4; ++nt) {
            const short8 Bf = *reinterpret_cast<const short8*>(&s_w2f[((kt * 4 + nt) * 64 + lane) * 4]);
#pragma unroll
            for (int t = 0; t < 4; ++t)
                acc[t][nt] = __builtin_amdgcn_mfma_f32_16x16x32_bf16(A[t], Bf, acc[t][nt], 0, 0, 0);
        }
    }

    // ---- heads: feature-major f2 tile, b64 writes, u16 reads ----
    const float hbias = wsf[WS_HBIAS + m];
    float b2v[4];
#pragma unroll
    for (int nt = 0; nt < 4; ++nt) b2v[nt] = wsf[WS_B2V + nt * 16 + m];
    const short8 hB0 = *reinterpret_cast<const short8*>(ws + WS_HBF + lane * 4);
    const short8 hB1 = *reinterpret_cast<const short8*>(ws + WS_HBF + 256 + lane * 4);

    unsigned short* f2b = reinterpret_cast<unsigned short*>(&s_buf[wv][0]);
    f32x4 ha[4];

#pragma unroll
    for (int t = 0; t < 4; ++t) {
        // write: lane owns feature f=nt*16+m, points q*4..q*4+3 -> one b64
#pragma unroll
        for (int nt = 0; nt < 4; ++nt) {
            const float v0 = fmaxf(acc[t][nt][0] + b2v[nt], 0.f);
            const float v1 = fmaxf(acc[t][nt][1] + b2v[nt], 0.f);
            const float v2 = fmaxf(acc[t][nt][2] + b2v[nt], 0.f);
            const float v3 = fmaxf(acc[t][nt][3] + b2v[nt], 0.f);
            uint2 u;
            u.x = cvtpk(v0, v1);
            u.y = cvtpk(v2, v3);
            *reinterpret_cast<uint2*>(&f2b[(nt * 16 + m) * FS + q * 4]) = u;
        }

        // read A-frags: lane = point m, features kt2*32 + q*8 + j
        short8 Afr[2];
#pragma unroll
        for (int kt2 = 0; kt2 < 2; ++kt2) {
            union { unsigned int u[4]; short8 s; } af;
#pragma unroll
            for (int jj = 0; jj < 4; ++jj) {
                const unsigned int lo = f2b[(kt2 * 32 + q * 8 + 2 * jj)     * FS + m];
                const unsigned int hi = f2b[(kt2 * 32 + q * 8 + 2 * jj + 1) * FS + m];
                af.u[jj] = lo | (hi << 16);
            }
            Afr[kt2] = af.s;
        }
        f32x4 h4 = {0, 0, 0, 0};
        h4 = __builtin_amdgcn_mfma_f32_16x16x32_bf16(Afr[0], hB0, h4, 0, 0, 0);
        h4 = __builtin_amdgcn_mfma_f32_16x16x32_bf16(Afr[1], hB1, h4, 0, 0, 0);
        ha[t] = h4;
    }

    // ---- xfer: redistribute 11 outs/point into per-wave LDS (f2 dead) ----
    float* xfer = reinterpret_cast<float*>(&s_buf[wv][0]);
    if (m < 11) {
#pragma unroll
        for (int t = 0; t < 4; ++t)
#pragma unroll
            for (int r = 0; r < 4; ++r)
                xfer[(t * 16 + q * 4 + r) * 11 + m] = ha[t][r] + hbias;
    }

    // ---- bc phase: lane i handles point pb0+i; stores ALL outputs ----
    float xv[11];
#pragma unroll
    for (int s = 0; s < 11; ++s) xv[s] = xfer[lane * 11 + s];

    const int n = pb0 + lane;
    const int b = n >> 16;
    const int h = (n >> 8) & 255;
    const int w = n & 255;

    // full-grid outputs, vectorized (replaces heads-loop divergent scatter)
    *reinterpret_cast<float2*>(&out[OFF_OFFSET + 2 * n]) = make_float2(xv[0], xv[1]);
    *reinterpret_cast<float4*>(&out[OFF_SPAK + 4 * n]) =
        make_float4(xv[7], xv[8], xv[9], xv[10]);

    if (h >= 5 && h < 251 && w >= 5 && w < 251) {
        const int hh = h - 5, ww = w - 5;
        const int tc = ((b * CROPD) + hh) * CROPD + ww;

        const float off0 = xv[0], off1 = xv[1];
        *reinterpret_cast<float2*>(&out[OFF_OOFF + 2 * tc]) = make_float2(off0, off1);
#pragma unroll
        for (int s = 0; s < 5; ++s) out[OFF_SPEKC + 5 * tc + s] = xv[2 + s];

        // grid-sample setup (gathers issued early)
        const float gx = fmaf((float)w, 2.0f / 255.0f, -1.0f) + off0 * (1.0f / 128.0f);
        const float gy = fmaf((float)h, 2.0f / 255.0f, -1.0f) + off1 * (1.0f / 128.0f);
        const float px = (gx + 1.0f) * 0.5f * 255.0f;
        const float py = (gy + 1.0f) * 0.5f * 255.0f;
        const float x0f = floorf(px), y0f = floorf(py);
        const float wx1 = px - x0f,  wy1 = py - y0f;
        const int x0 = (int)x0f, y0 = (int)y0f;
        const int x1 = x0 + 1,  y1 = y0 + 1;
        const bool vx0 = (x0 >= 0) & (x0 < 256);
        const bool vx1 = (x1 >= 0) & (x1 < 256);
        const bool vy0 = (y0 >= 0) & (y0 < 256);
        const bool vy1 = (y1 >= 0) & (y1 < 256);
        const int cx0 = min(max(x0, 0), 255), cx1 = min(max(x1, 0), 255);
        const int cy0 = min(max(y0, 0), 255), cy1 = min(max(y1, 0), 255);
        const float w00 = (1.0f - wy1) * (1.0f - wx1) * (float)(vy0 & vx0);
        const float w01 = (1.0f - wy1) * wx1          * (float)(vy0 & vx1);
        const float w10 = wy1 * (1.0f - wx1)          * (float)(vy1 & vx0);
        const float w11 = wy1 * wx1                   * (float)(vy1 & vx1);
        const int i00 = cy0 * 256 + cx0;
        const int i01 = cy0 * 256 + cx1;
        const int i10 = cy1 * 256 + cx0;
        const int i11 = cy1 * 256 + cx1;
        const float* mb = msi + ((size_t)b * 4) * 65536;
        float m00[4], m01[4], m10[4], m11[4];
#pragma unroll
        for (int ch = 0; ch < 4; ++ch) {
            const float* mc = mb + ch * 65536;
            m00[ch] = mc[i00]; m01[ch] = mc[i01]; m10[ch] = mc[i10]; m11[ch] = mc[i11];
        }

        // spatially-variant conv, central symmetry; exp2-space fwd-diff.
        const float a = xv[7], c = xv[9], d = xv[10];
        const float inv00 = a * a + c * c;
        const float inv01 = c * d;
        const float inv11 = d * d;
        const float c00 = -0.72134752f * inv00;
        const float c01 = -1.44269504f * inv01;
        const float c11 = -0.72134752f * inv11;
        const float* prow = pan + ((size_t)b << 20) + (size_t)(4 * h - 6) * 1024 + (4 * w - 6);

        float ksum = 1.0f;
        float conv = prow[7 * 1024 + 7];
        {
            float arg = c11;
            float dk  = 3.0f * c11;
#pragma unroll
            for (int k = 1; k <= 7; ++k) {
                const float kv = __builtin_amdgcn_exp2f(arg);
                ksum += 2.0f * kv;
                conv = fmaf(kv, prow[7 * 1024 + 7 - k] + prow[7 * 1024 + 7 + k], conv);
                arg += dk; dk += 2.0f * c11;
            }
        }
#pragma unroll 1
        for (int p = 0; p < 7; ++p) {            // rows p & 14-p
            const float gp = (float)(p - 7);
            const float cg = c01 * gp;
            float arg = fmaf(cg, -7.0f, fmaf(c00 * gp, gp, 49.0f * c11));
            float dq  = fmaf(-13.0f, c11, cg);
            const float dd = 2.0f * c11;
            const float* pa = prow + p * 1024;
            const float* pc = prow + (14 - p) * 1024;
#pragma unroll
            for (int qq = 0; qq < 15; ++qq) {
                const float kv = __builtin_amdgcn_exp2f(arg);
                ksum += 2.0f * kv;
                conv = fmaf(kv, pa[qq] + pc[14 - qq], conv);
                arg += dq; dq += dd;
            }
        }
        out[OFF_PREPAN + tc] = conv / ksum;

        // finish sample + pre_msi
        float pm = xv[6];
#pragma unroll
        for (int ch = 0; ch < 4; ++ch) {
            const float v = w00 * m00[ch] + w01 * m01[ch] + w10 * m10[ch] + w11 * m11[ch];
            out[OFF_OMSI + (((b * 4) + ch) * CROPD + hh) * CROPD + ww] = v;
            pm = fmaf(v, xv[2 + ch], pm);
        }
        out[OFF_PREMSI + tc] = pm;
    }
}

extern "C" void kernel_launch(void* const* d_in, const int* in_sizes, int n_in,
                              void* d_out, int out_size, void* d_ws, size_t ws_size,
                              hipStream_t stream)
{
    const float* msi    = (const float*)d_in[0];
    const float* pan    = (const float*)d_in[1];
    const float* coords = (const float*)d_in[2];
    const float* w1  = (const float*)d_in[3];
    const float* b1  = (const float*)d_in[4];
    const float* w2  = (const float*)d_in[5];
    const float* b2  = (const float*)d_in[6];
    const float* wo  = (const float*)d_in[7];
    const float* bo  = (const float*)d_in[8];
    const float* wse = (const float*)d_in[9];
    const float* bse = (const float*)d_in[10];
    const float* wsa = (const float*)d_in[11];
    const float* bsa = (const float*)d_in[12];
    float* out = (float*)d_out;
    unsigned int* ws = (unsigned int*)d_ws;

    prep_kernel<<<(WS_NDW + 255) / 256, 256, 0, stream>>>(
        w1, b1, w2, b2, wo, bo, wse, bse, wsa, bsa, ws);
    fused_kernel<<<1024, 256, 0, stream>>>(coords, ws, pan, msi, out);
}

// Round 14
// 34.989 us; speedup vs baseline: 1.2987x; 1.0256x over previous
//
#include <hip/hip_runtime.h>
#include <hip/hip_bf16.h>
#include <math.h>

typedef __attribute__((ext_vector_type(8))) short short8;
typedef __attribute__((ext_vector_type(4))) float f32x4;

namespace {
constexpr int BS    = 4;
constexpr int LSZ   = 256;
constexpr int CROPD = 246;
constexpr int NPTS  = BS * LSZ * LSZ;      // 262144
constexpr int NCROP = BS * CROPD * CROPD;  // 242064

constexpr int SZ_OMSI   = BS * 4 * CROPD * CROPD;
constexpr int SZ_OOFF   = BS * CROPD * CROPD * 2;
constexpr int SZ_PREMSI = BS * CROPD * CROPD;
constexpr int SZ_PREPAN = BS * CROPD * CROPD;
constexpr int SZ_OFFSET = NPTS * 2;
constexpr int SZ_SPEKC  = BS * CROPD * CROPD * 5;

constexpr int OFF_OMSI   = 0;
constexpr int OFF_OOFF   = OFF_OMSI + SZ_OMSI;
constexpr int OFF_PREMSI = OFF_OOFF + SZ_OOFF;
constexpr int OFF_PREPAN = OFF_PREMSI + SZ_PREMSI;
constexpr int OFF_OFFSET = OFF_PREPAN + SZ_PREPAN;
constexpr int OFF_SPEKC  = OFF_OFFSET + SZ_OFFSET;
constexpr int OFF_SPAK   = OFF_SPEKC + SZ_SPEKC;

// d_ws dword layout (prep_kernel output):
constexpr int WS_W2F   = 0;     // 7168 dw : w2 B-fragments (bf16 pairs)
constexpr int WS_HBF   = 7168;  //  512 dw : head B-fragments (bf16 pairs)
constexpr int WS_W1F   = 7680;  //  224 dw : layer-1 A-frags, PERMUTED [kt][i][fr]
constexpr int WS_B1T   = 7904;  //  224 dw : b1 f32, [kt][q][j] (= MFMA C-init)
constexpr int WS_B2V   = 8128;  //   64 dw : b2 padded to [4][16] f32
constexpr int WS_HBIAS = 8192;  //   16 dw : head biases per out-slot
constexpr int WS_NDW   = 8208;

constexpr int FS = 20;          // f2 feature-row stride in ushorts (40 B)
} // namespace

static __device__ __forceinline__ unsigned short bf16u(float x) {
    __hip_bfloat16 h = __float2bfloat16(x);
    return __builtin_bit_cast(unsigned short, h);
}
static __device__ __forceinline__ unsigned int pk2(float a, float b) {
    return (unsigned int)bf16u(a) | ((unsigned int)bf16u(b) << 16);
}
// HW packed f32->bf16 (RNE), 1 instr. [T12 recipe]
static __device__ __forceinline__ unsigned int cvtpk(float lo, float hi) {
    unsigned int r;
    asm("v_cvt_pk_bf16_f32 %0, %1, %2" : "=v"(r) : "v"(lo), "v"(hi));
    return r;
}

// ---------------- prep: pack all weights into d_ws (runs every call) -------
__global__ __launch_bounds__(256) void prep_kernel(
    const float* __restrict__ w1, const float* __restrict__ b1,
    const float* __restrict__ w2, const float* __restrict__ b2,
    const float* __restrict__ wo, const float* __restrict__ bo,
    const float* __restrict__ wse, const float* __restrict__ bse,
    const float* __restrict__ wsa, const float* __restrict__ bsa,
    unsigned int* __restrict__ ws)
{
    const int d = blockIdx.x * 256 + threadIdx.x;
    if (d < 7168) {                       // W2F
        const int pi = d >> 8, rem = d & 255, lane = rem >> 2, jj = rem & 3;
        const int kt = pi >> 2, nt = pi & 3, q = lane >> 4, m = lane & 15;
        const int r0 = kt * 32 + q * 8 + 2 * jj, col = nt * 16 + m;
        const float v0 = (col < 50 && r0     < 200) ? w2[r0 * 50 + col]       : 0.f;
        const float v1 = (col < 50 && r0 + 1 < 200) ? w2[(r0 + 1) * 50 + col] : 0.f;
        ws[d] = pk2(v0, v1);
    } else if (d < 7680) {                // HBF
        const int e = d - 7168;
        const int kt2 = e >> 8, rem = e & 255, lane = rem >> 2, jj = rem & 3;
        const int q = lane >> 4, m = lane & 15;
        float v[2];
#pragma unroll
        for (int hlf = 0; hlf < 2; ++hlf) {
            const int f = kt2 * 32 + q * 8 + 2 * jj + hlf;
            float val = 0.f;
            if (f < 50 && m < 11) {
                if      (m < 2) val = wo [f * 2 + m];
                else if (m < 7) val = wse[f * 5 + (m - 2)];
                else            val = wsa[f * 4 + (m - 7)];
            }
            v[hlf] = val;
        }
        ws[d] = pk2(v[0], v[1]);
    } else if (d < 7904) {                // W1F: layer-1 A-frags, permuted
        // A-frag row fr of MFMA-i in block kt holds LOGICAL feature
        // L = 32kt + 8*(fr>>2) + 4i + (fr&3), so that the layer-1 MFMA's
        // C-layout (lane(q,m) reg r = feature 32kt+8q+4i+r) exactly matches
        // layer-2's A-frag k-order (slot j = 4i+r). Only k=0,1 are used.
        const int e = d - 7680;
        const int kt = e >> 5, i = (e >> 4) & 1, fr = e & 15;
        const int L = 32 * kt + 8 * (fr >> 2) + 4 * i + (fr & 3);
        const float va = (L < 200) ? w1[L]       : 0.f;
        const float vb = (L < 200) ? w1[200 + L] : 0.f;
        ws[d] = pk2(va, vb);
    } else if (d < 8128) {                // B1T (f32) — doubles as MFMA C-init
        const int e = d - 7904;
        const int kt = e >> 5, q = (e >> 3) & 3, j = e & 7;
        const int k = kt * 32 + q * 8 + j;
        ws[d] = __float_as_uint((k < 200) ? b1[k] : 0.f);
    } else if (d < 8192) {                // B2V
        const int e = d - 8128;
        const int f = (e >> 4) * 16 + (e & 15);
        ws[d] = __float_as_uint((f < 50) ? b2[f] : 0.f);
    } else if (d < WS_NDW) {              // HBIAS
        const int m = d - 8192;
        const float v = (m < 2) ? bo[m] : (m < 7) ? bse[m - 2] : (m < 11) ? bsa[m - 7] : 0.f;
        ws[d] = __float_as_uint(v);
    }
}

// ---------------- fused: MLP (all-MFMA) + conv + grid-sample ---------------
// R14: VALU-issue diet (R13 accounting: ~1800 instr/wave x 16 waves/SIMD
// ~= 24us pure issue = the bound).
//  (a) layer-1 as MFMA: D = w1^T . coords^T + b1 (K=2 padded to 32),
//      feature-permuted in prep so D-regs feed layer-2 A-frags directly;
//      bias folded into MFMA C-operand. ~530 -> ~250 VALU instr/wave.
//  (b) conv kv via multiplicative forward differencing: 2nd difference of
//      the quadratic exp2-arg is constant -> kv*=r, r*=s per tap; 17 exps
//      per point instead of 113 (v_exp is quarter-rate).
__global__ __launch_bounds__(256, 4) void fused_kernel(
    const float* __restrict__ coords,
    const unsigned int* __restrict__ ws,
    const float* __restrict__ pan,
    const float* __restrict__ msi,
    float* __restrict__ out)
{
    __shared__ __align__(16) unsigned int  s_w2f[7168];      // 28672 B
    __shared__ __align__(16) unsigned int  s_w1f[224];       //   896 B
    __shared__ __align__(16) unsigned char s_buf[4][2816];   // 11264 B
    // total 40832 B <= 40960 -> 4 blocks/CU
    // per-wave s_buf: phase1 = f2T [64 feat][20] ushort; phase2 = xfer 64x11 f32

    const int tid  = threadIdx.x;
    const int lane = tid & 63;
    const int wv   = tid >> 6;
    const int q    = lane >> 4;
    const int m    = lane & 15;
    const float* wsf = reinterpret_cast<const float*>(ws);

    const int pb0 = (blockIdx.x * 4 + wv) * 64;   // 1024 blocks, 64 pts/wave

    float2 cc[4];
#pragma unroll
    for (int t = 0; t < 4; ++t)
        cc[t] = reinterpret_cast<const float2*>(coords)[pb0 + t * 16 + m];

    // stage W2F (1792 uint4) + W1F (224 dw) into LDS
    {
        const uint4* __restrict__ g4 = reinterpret_cast<const uint4*>(ws);
        uint4* __restrict__ s4 = reinterpret_cast<uint4*>(s_w2f);
#pragma unroll 1
        for (int i = 0; i < 7; ++i) s4[tid + i * 256] = g4[tid + i * 256];
        if (tid < 224) s_w1f[tid] = ws[WS_W1F + tid];
    }
    __syncthreads();

    // ---- coords B-fragments (K=2 in k-slots 0,1; rest zero) ----
    short8 Bc[4];
#pragma unroll
    for (int t = 0; t < 4; ++t) {
        union { unsigned int u[4]; short8 s; } b;
        b.u[0] = (q == 0) ? cvtpk(cc[t].x, cc[t].y) : 0u;
        b.u[1] = 0u; b.u[2] = 0u; b.u[3] = 0u;
        Bc[t] = b.s;
    }

    // ---- layer 1 (MFMA, bias in C) + layer 2 GEMM, ROLLED kt loop ----
    f32x4 acc[4][4];
#pragma unroll
    for (int t = 0; t < 4; ++t)
#pragma unroll
        for (int nt = 0; nt < 4; ++nt) acc[t][nt] = (f32x4){0, 0, 0, 0};

#pragma unroll 1
    for (int kt = 0; kt < 7; ++kt) {
        const float4 bb0 = *reinterpret_cast<const float4*>(wsf + WS_B1T + kt * 32 + q * 8);
        const float4 bb1 = *reinterpret_cast<const float4*>(wsf + WS_B1T + kt * 32 + q * 8 + 4);
        const unsigned int w1lo = s_w1f[kt * 32 + m];        // MFMA-0 frag
        const unsigned int w1hi = s_w1f[kt * 32 + 16 + m];   // MFMA-1 frag
        union { unsigned int u[4]; short8 s; } a0, a1;
        a0.u[0] = (q == 0) ? w1lo : 0u; a0.u[1] = 0u; a0.u[2] = 0u; a0.u[3] = 0u;
        a1.u[0] = (q == 0) ? w1hi : 0u; a1.u[1] = 0u; a1.u[2] = 0u; a1.u[3] = 0u;
        const f32x4 bias0 = {bb0.x, bb0.y, bb0.z, bb0.w};
        const f32x4 bias1 = {bb1.x, bb1.y, bb1.z, bb1.w};

        short8 A[4];
#pragma unroll
        for (int t = 0; t < 4; ++t) {
            f32x4 d0 = __builtin_amdgcn_mfma_f32_16x16x32_bf16(a0.s, Bc[t], bias0, 0, 0, 0);
            f32x4 d1 = __builtin_amdgcn_mfma_f32_16x16x32_bf16(a1.s, Bc[t], bias1, 0, 0, 0);
            d0 = __builtin_elementwise_max(d0, (f32x4){0.f, 0.f, 0.f, 0.f});
            d1 = __builtin_elementwise_max(d1, (f32x4){0.f, 0.f, 0.f, 0.f});
            union { unsigned int u[4]; short8 s; } af;
            af.u[0] = cvtpk(d0[0], d0[1]);
            af.u[1] = cvtpk(d0[2], d0[3]);
            af.u[2] = cvtpk(d1[0], d1[1]);
            af.u[3] = cvtpk(d1[2], d1[3]);
            A[t] = af.s;
        }
#pragma unroll
        for (int nt = 0; nt < 4; ++nt) {
            const short8 Bf = *reinterpret_cast<const short8*>(&s_w2f[((kt * 4 + nt) * 64 + lane) * 4]);
#pragma unroll
            for (int t = 0; t < 4; ++t)
                acc[t][nt] = __builtin_amdgcn_mfma_f32_16x16x32_bf16(A[t], Bf, acc[t][nt], 0, 0, 0);
        }
    }

    // ---- heads: feature-major f2 tile, b64 writes, u16 reads ----
    const float hbias = wsf[WS_HBIAS + m];
    float b2v[4];
#pragma unroll
    for (int nt = 0; nt < 4; ++nt) b2v[nt] = wsf[WS_B2V + nt * 16 + m];
    const short8 hB0 = *reinterpret_cast<const short8*>(ws + WS_HBF + lane * 4);
    const short8 hB1 = *reinterpret_cast<const short8*>(ws + WS_HBF + 256 + lane * 4);

    unsigned short* f2b = reinterpret_cast<unsigned short*>(&s_buf[wv][0]);
    f32x4 ha[4];

#pragma unroll
    for (int t = 0; t < 4; ++t) {
#pragma unroll
        for (int nt = 0; nt < 4; ++nt) {
            const float v0 = fmaxf(acc[t][nt][0] + b2v[nt], 0.f);
            const float v1 = fmaxf(acc[t][nt][1] + b2v[nt], 0.f);
            const float v2 = fmaxf(acc[t][nt][2] + b2v[nt], 0.f);
            const float v3 = fmaxf(acc[t][nt][3] + b2v[nt], 0.f);
            uint2 u;
            u.x = cvtpk(v0, v1);
            u.y = cvtpk(v2, v3);
            *reinterpret_cast<uint2*>(&f2b[(nt * 16 + m) * FS + q * 4]) = u;
        }

        short8 Afr[2];
#pragma unroll
        for (int kt2 = 0; kt2 < 2; ++kt2) {
            union { unsigned int u[4]; short8 s; } af;
#pragma unroll
            for (int jj = 0; jj < 4; ++jj) {
                const unsigned int lo = f2b[(kt2 * 32 + q * 8 + 2 * jj)     * FS + m];
                const unsigned int hi = f2b[(kt2 * 32 + q * 8 + 2 * jj + 1) * FS + m];
                af.u[jj] = lo | (hi << 16);
            }
            Afr[kt2] = af.s;
        }
        f32x4 h4 = {0, 0, 0, 0};
        h4 = __builtin_amdgcn_mfma_f32_16x16x32_bf16(Afr[0], hB0, h4, 0, 0, 0);
        h4 = __builtin_amdgcn_mfma_f32_16x16x32_bf16(Afr[1], hB1, h4, 0, 0, 0);
        ha[t] = h4;
    }

    // ---- xfer: redistribute 11 outs/point into per-wave LDS (f2 dead) ----
    float* xfer = reinterpret_cast<float*>(&s_buf[wv][0]);
    if (m < 11) {
#pragma unroll
        for (int t = 0; t < 4; ++t)
#pragma unroll
            for (int r = 0; r < 4; ++r)
                xfer[(t * 16 + q * 4 + r) * 11 + m] = ha[t][r] + hbias;
    }

    // ---- bc phase: lane i handles point pb0+i; stores ALL outputs ----
    float xv[11];
#pragma unroll
    for (int s = 0; s < 11; ++s) xv[s] = xfer[lane * 11 + s];

    const int n = pb0 + lane;
    const int b = n >> 16;
    const int h = (n >> 8) & 255;
    const int w = n & 255;

    *reinterpret_cast<float2*>(&out[OFF_OFFSET + 2 * n]) = make_float2(xv[0], xv[1]);
    *reinterpret_cast<float4*>(&out[OFF_SPAK + 4 * n]) =
        make_float4(xv[7], xv[8], xv[9], xv[10]);

    if (h >= 5 && h < 251 && w >= 5 && w < 251) {
        const int hh = h - 5, ww = w - 5;
        const int tc = ((b * CROPD) + hh) * CROPD + ww;

        const float off0 = xv[0], off1 = xv[1];
        *reinterpret_cast<float2*>(&out[OFF_OOFF + 2 * tc]) = make_float2(off0, off1);
#pragma unroll
        for (int s = 0; s < 5; ++s) out[OFF_SPEKC + 5 * tc + s] = xv[2 + s];

        // grid-sample setup (gathers issued early)
        const float gx = fmaf((float)w, 2.0f / 255.0f, -1.0f) + off0 * (1.0f / 128.0f);
        const float gy = fmaf((float)h, 2.0f / 255.0f, -1.0f) + off1 * (1.0f / 128.0f);
        const float px = (gx + 1.0f) * 0.5f * 255.0f;
        const float py = (gy + 1.0f) * 0.5f * 255.0f;
        const float x0f = floorf(px), y0f = floorf(py);
        const float wx1 = px - x0f,  wy1 = py - y0f;
        const int x0 = (int)x0f, y0 = (int)y0f;
        const int x1 = x0 + 1,  y1 = y0 + 1;
        const bool vx0 = (x0 >= 0) & (x0 < 256);
        const bool vx1 = (x1 >= 0) & (x1 < 256);
        const bool vy0 = (y0 >= 0) & (y0 < 256);
        const bool vy1 = (y1 >= 0) & (y1 < 256);
        const int cx0 = min(max(x0, 0), 255), cx1 = min(max(x1, 0), 255);
        const int cy0 = min(max(y0, 0), 255), cy1 = min(max(y1, 0), 255);
        const float w00 = (1.0f - wy1) * (1.0f - wx1) * (float)(vy0 & vx0);
        const float w01 = (1.0f - wy1) * wx1          * (float)(vy0 & vx1);
        const float w10 = wy1 * (1.0f - wx1)          * (float)(vy1 & vx0);
        const float w11 = wy1 * wx1                   * (float)(vy1 & vx1);
        const int i00 = cy0 * 256 + cx0;
        const int i01 = cy0 * 256 + cx1;
        const int i10 = cy1 * 256 + cx0;
        const int i11 = cy1 * 256 + cx1;
        const float* mb = msi + ((size_t)b * 4) * 65536;
        float m00[4], m01[4], m10[4], m11[4];
#pragma unroll
        for (int ch = 0; ch < 4; ++ch) {
            const float* mc = mb + ch * 65536;
            m00[ch] = mc[i00]; m01[ch] = mc[i01]; m10[ch] = mc[i10]; m11[ch] = mc[i11];
        }

        // conv: multiplicative forward differencing in exp2 space.
        // kv(q+1) = kv(q)*r(q); r(q+1) = r(q)*s, s = exp2(2*c11) const.
        const float a = xv[7], c = xv[9], d = xv[10];
        const float inv00 = a * a + c * c;
        const float inv01 = c * d;
        const float inv11 = d * d;
        const float c00 = -0.72134752f * inv00;
        const float c01 = -1.44269504f * inv01;
        const float c11 = -0.72134752f * inv11;
        const float* prow = pan + ((size_t)b << 20) + (size_t)(4 * h - 6) * 1024 + (4 * w - 6);

        const float s2 = __builtin_amdgcn_exp2f(2.0f * c11);
        float ksh  = 0.0f;                       // half-sum, excludes center
        float conv = prow[7 * 1024 + 7];
        {
            // row 7 (gp=0): arg(k) = c11*k^2
            float kv = __builtin_amdgcn_exp2f(c11);
            float rr = __builtin_amdgcn_exp2f(3.0f * c11);
#pragma unroll
            for (int k = 1; k <= 7; ++k) {
                conv = fmaf(kv, prow[7 * 1024 + 7 - k] + prow[7 * 1024 + 7 + k], conv);
                ksh += kv;
                kv *= rr; rr *= s2;
            }
        }
#pragma unroll 1
        for (int p = 0; p < 7; ++p) {            // rows p & 14-p
            const float gp = (float)(p - 7);
            const float cg = c01 * gp;
            float kv = __builtin_amdgcn_exp2f(fmaf(cg, -7.0f, fmaf(c00 * gp, gp, 49.0f * c11)));
            float rr = __builtin_amdgcn_exp2f(fmaf(-13.0f, c11, cg));
            const float* pa = prow + p * 1024;
            const float* pc = prow + (14 - p) * 1024;
#pragma unroll
            for (int qq = 0; qq < 15; ++qq) {
                conv = fmaf(kv, pa[qq] + pc[14 - qq], conv);
                ksh += kv;
                kv *= rr; rr *= s2;
            }
        }
        const float ksum = fmaf(2.0f, ksh, 1.0f);
        out[OFF_PREPAN + tc] = conv / ksum;

        // finish sample + pre_msi
        float pm = xv[6];
#pragma unroll
        for (int ch = 0; ch < 4; ++ch) {
            const float v = w00 * m00[ch] + w01 * m01[ch] + w10 * m10[ch] + w11 * m11[ch];
            out[OFF_OMSI + (((b * 4) + ch) * CROPD + hh) * CROPD + ww] = v;
            pm = fmaf(v, xv[2 + ch], pm);
        }
        out[OFF_PREMSI + tc] = pm;
    }
}

extern "C" void kernel_launch(void* const* d_in, const int* in_sizes, int n_in,
                              void* d_out, int out_size, void* d_ws, size_t ws_size,
                              hipStream_t stream)
{
    const float* msi    = (const float*)d_in[0];
    const float* pan    = (const float*)d_in[1];
    const float* coords = (const float*)d_in[2];
    const float* w1  = (const float*)d_in[3];
    const float* b1  = (const float*)d_in[4];
    const float* w2  = (const float*)d_in[5];
    const float* b2  = (const float*)d_in[6];
    const float* wo  = (const float*)d_in[7];
    const float* bo  = (const float*)d_in[8];
    const float* wse = (const float*)d_in[9];
    const float* bse = (const float*)d_in[10];
    const float* wsa = (const float*)d_in[11];
    const float* bsa = (const float*)d_in[12];
    float* out = (float*)d_out;
    unsigned int* ws = (unsigned int*)d_ws;

    prep_kernel<<<(WS_NDW + 255) / 256, 256, 0, stream>>>(
        w1, b1, w2, b2, wo, bo, wse, bse, wsa, bsa, ws);
    fused_kernel<<<1024, 256, 0, stream>>>(coords, ws, pan, msi, out);
}

// Round 15
// 34.982 us; speedup vs baseline: 1.2990x; 1.0002x over previous
//
#include <hip/hip_runtime.h>
#include <hip/hip_bf16.h>
#include <math.h>

typedef __attribute__((ext_vector_type(8))) short short8;
typedef __attribute__((ext_vector_type(4))) float f32x4;

namespace {
constexpr int BS    = 4;
constexpr int LSZ   = 256;
constexpr int CROPD = 246;
constexpr int NPTS  = BS * LSZ * LSZ;      // 262144
constexpr int NCROP = BS * CROPD * CROPD;  // 242064

constexpr int SZ_OMSI   = BS * 4 * CROPD * CROPD;
constexpr int SZ_OOFF   = BS * CROPD * CROPD * 2;
constexpr int SZ_PREMSI = BS * CROPD * CROPD;
constexpr int SZ_PREPAN = BS * CROPD * CROPD;
constexpr int SZ_OFFSET = NPTS * 2;
constexpr int SZ_SPEKC  = BS * CROPD * CROPD * 5;

constexpr int OFF_OMSI   = 0;
constexpr int OFF_OOFF   = OFF_OMSI + SZ_OMSI;
constexpr int OFF_PREMSI = OFF_OOFF + SZ_OOFF;
constexpr int OFF_PREPAN = OFF_PREMSI + SZ_PREMSI;
constexpr int OFF_OFFSET = OFF_PREPAN + SZ_PREPAN;
constexpr int OFF_SPEKC  = OFF_OFFSET + SZ_OFFSET;
constexpr int OFF_SPAK   = OFF_SPEKC + SZ_SPEKC;

// d_ws dword layout (prep_kernel output):
constexpr int WS_W2F   = 0;     // 7168 dw : w2 B-fragments (bf16 pairs)
constexpr int WS_HBF   = 7168;  //  512 dw : head B-fragments (bf16 pairs)
constexpr int WS_W1F   = 7680;  //  224 dw : layer-1 A-frags, PERMUTED [kt][i][fr]
constexpr int WS_B1T   = 7904;  //  224 dw : b1 f32, [kt][q][j] (= MFMA C-init)
constexpr int WS_B2V   = 8128;  //   64 dw : b2 padded to [4][16] f32
constexpr int WS_HBIAS = 8192;  //   16 dw : head biases per out-slot
constexpr int WS_NDW   = 8208;

constexpr int FS = 20;          // f2 feature-row stride in ushorts (40 B)
} // namespace

static __device__ __forceinline__ unsigned short bf16u(float x) {
    __hip_bfloat16 h = __float2bfloat16(x);
    return __builtin_bit_cast(unsigned short, h);
}
static __device__ __forceinline__ unsigned int pk2(float a, float b) {
    return (unsigned int)bf16u(a) | ((unsigned int)bf16u(b) << 16);
}
// HW packed f32->bf16 (RNE), 1 instr. [T12 recipe]
static __device__ __forceinline__ unsigned int cvtpk(float lo, float hi) {
    unsigned int r;
    asm("v_cvt_pk_bf16_f32 %0, %1, %2" : "=v"(r) : "v"(lo), "v"(hi));
    return r;
}

// ---------------- prep: pack all weights into d_ws (runs every call) -------
__global__ __launch_bounds__(256) void prep_kernel(
    const float* __restrict__ w1, const float* __restrict__ b1,
    const float* __restrict__ w2, const float* __restrict__ b2,
    const float* __restrict__ wo, const float* __restrict__ bo,
    const float* __restrict__ wse, const float* __restrict__ bse,
    const float* __restrict__ wsa, const float* __restrict__ bsa,
    unsigned int* __restrict__ ws)
{
    const int d = blockIdx.x * 256 + threadIdx.x;
    if (d < 7168) {                       // W2F
        const int pi = d >> 8, rem = d & 255, lane = rem >> 2, jj = rem & 3;
        const int kt = pi >> 2, nt = pi & 3, q = lane >> 4, m = lane & 15;
        const int r0 = kt * 32 + q * 8 + 2 * jj, col = nt * 16 + m;
        const float v0 = (col < 50 && r0     < 200) ? w2[r0 * 50 + col]       : 0.f;
        const float v1 = (col < 50 && r0 + 1 < 200) ? w2[(r0 + 1) * 50 + col] : 0.f;
        ws[d] = pk2(v0, v1);
    } else if (d < 7680) {                // HBF
        const int e = d - 7168;
        const int kt2 = e >> 8, rem = e & 255, lane = rem >> 2, jj = rem & 3;
        const int q = lane >> 4, m = lane & 15;
        float v[2];
#pragma unroll
        for (int hlf = 0; hlf < 2; ++hlf) {
            const int f = kt2 * 32 + q * 8 + 2 * jj + hlf;
            float val = 0.f;
            if (f < 50 && m < 11) {
                if      (m < 2) val = wo [f * 2 + m];
                else if (m < 7) val = wse[f * 5 + (m - 2)];
                else            val = wsa[f * 4 + (m - 7)];
            }
            v[hlf] = val;
        }
        ws[d] = pk2(v[0], v[1]);
    } else if (d < 7904) {                // W1F: layer-1 A-frags, permuted
        const int e = d - 7680;
        const int kt = e >> 5, i = (e >> 4) & 1, fr = e & 15;
        const int L = 32 * kt + 8 * (fr >> 2) + 4 * i + (fr & 3);
        const float va = (L < 200) ? w1[L]       : 0.f;
        const float vb = (L < 200) ? w1[200 + L] : 0.f;
        ws[d] = pk2(va, vb);
    } else if (d < 8128) {                // B1T (f32) — doubles as MFMA C-init
        const int e = d - 7904;
        const int kt = e >> 5, q = (e >> 3) & 3, j = e & 7;
        const int k = kt * 32 + q * 8 + j;
        ws[d] = __float_as_uint((k < 200) ? b1[k] : 0.f);
    } else if (d < 8192) {                // B2V
        const int e = d - 8128;
        const int f = (e >> 4) * 16 + (e & 15);
        ws[d] = __float_as_uint((f < 50) ? b2[f] : 0.f);
    } else if (d < WS_NDW) {              // HBIAS
        const int m = d - 8192;
        const float v = (m < 2) ? bo[m] : (m < 7) ? bse[m - 2] : (m < 11) ? bsa[m - 7] : 0.f;
        ws[d] = __float_as_uint(v);
    }
}

// ---------------- fused: MLP (all-MFMA) + conv + grid-sample ---------------
// R15: conv pan reads vectorized as 5 ALIGNED float4/row (base col 4w-8 is
// 16B-aligned for all w; taps at f[2..16]). Per row-pair: 10 coalesced loads
// (~16 cyc L1 service each) replacing 30 scalar loads (~17 cyc each) -> conv
// L1 service/wave 3825 -> ~900 cyc. R7 tested this in the I-FETCH-BOUND
// regime (null, masked); retest in the small-code regime (rolled row loop).
// Everything else identical to R14.
__global__ __launch_bounds__(256, 4) void fused_kernel(
    const float* __restrict__ coords,
    const unsigned int* __restrict__ ws,
    const float* __restrict__ pan,
    const float* __restrict__ msi,
    float* __restrict__ out)
{
    __shared__ __align__(16) unsigned int  s_w2f[7168];      // 28672 B
    __shared__ __align__(16) unsigned int  s_w1f[224];       //   896 B
    __shared__ __align__(16) unsigned char s_buf[4][2816];   // 11264 B
    // total 40832 B <= 40960 -> 4 blocks/CU

    const int tid  = threadIdx.x;
    const int lane = tid & 63;
    const int wv   = tid >> 6;
    const int q    = lane >> 4;
    const int m    = lane & 15;
    const float* wsf = reinterpret_cast<const float*>(ws);

    const int pb0 = (blockIdx.x * 4 + wv) * 64;   // 1024 blocks, 64 pts/wave

    float2 cc[4];
#pragma unroll
    for (int t = 0; t < 4; ++t)
        cc[t] = reinterpret_cast<const float2*>(coords)[pb0 + t * 16 + m];

    // stage W2F (1792 uint4) + W1F (224 dw) into LDS
    {
        const uint4* __restrict__ g4 = reinterpret_cast<const uint4*>(ws);
        uint4* __restrict__ s4 = reinterpret_cast<uint4*>(s_w2f);
#pragma unroll 1
        for (int i = 0; i < 7; ++i) s4[tid + i * 256] = g4[tid + i * 256];
        if (tid < 224) s_w1f[tid] = ws[WS_W1F + tid];
    }
    __syncthreads();

    // ---- coords B-fragments (K=2 in k-slots 0,1; rest zero) ----
    short8 Bc[4];
#pragma unroll
    for (int t = 0; t < 4; ++t) {
        union { unsigned int u[4]; short8 s; } b;
        b.u[0] = (q == 0) ? cvtpk(cc[t].x, cc[t].y) : 0u;
        b.u[1] = 0u; b.u[2] = 0u; b.u[3] = 0u;
        Bc[t] = b.s;
    }

    // ---- layer 1 (MFMA, bias in C) + layer 2 GEMM, ROLLED kt loop ----
    f32x4 acc[4][4];
#pragma unroll
    for (int t = 0; t < 4; ++t)
#pragma unroll
        for (int nt = 0; nt < 4; ++nt) acc[t][nt] = (f32x4){0, 0, 0, 0};

#pragma unroll 1
    for (int kt = 0; kt < 7; ++kt) {
        const float4 bb0 = *reinterpret_cast<const float4*>(wsf + WS_B1T + kt * 32 + q * 8);
        const float4 bb1 = *reinterpret_cast<const float4*>(wsf + WS_B1T + kt * 32 + q * 8 + 4);
        const unsigned int w1lo = s_w1f[kt * 32 + m];        // MFMA-0 frag
        const unsigned int w1hi = s_w1f[kt * 32 + 16 + m];   // MFMA-1 frag
        union { unsigned int u[4]; short8 s; } a0, a1;
        a0.u[0] = (q == 0) ? w1lo : 0u; a0.u[1] = 0u; a0.u[2] = 0u; a0.u[3] = 0u;
        a1.u[0] = (q == 0) ? w1hi : 0u; a1.u[1] = 0u; a1.u[2] = 0u; a1.u[3] = 0u;
        const f32x4 bias0 = {bb0.x, bb0.y, bb0.z, bb0.w};
        const f32x4 bias1 = {bb1.x, bb1.y, bb1.z, bb1.w};

        short8 A[4];
#pragma unroll
        for (int t = 0; t < 4; ++t) {
            f32x4 d0 = __builtin_amdgcn_mfma_f32_16x16x32_bf16(a0.s, Bc[t], bias0, 0, 0, 0);
            f32x4 d1 = __builtin_amdgcn_mfma_f32_16x16x32_bf16(a1.s, Bc[t], bias1, 0, 0, 0);
            d0 = __builtin_elementwise_max(d0, (f32x4){0.f, 0.f, 0.f, 0.f});
            d1 = __builtin_elementwise_max(d1, (f32x4){0.f, 0.f, 0.f, 0.f});
            union { unsigned int u[4]; short8 s; } af;
            af.u[0] = cvtpk(d0[0], d0[1]);
            af.u[1] = cvtpk(d0[2], d0[3]);
            af.u[2] = cvtpk(d1[0], d1[1]);
            af.u[3] = cvtpk(d1[2], d1[3]);
            A[t] = af.s;
        }
#pragma unroll
        for (int nt = 0; nt < 4; ++nt) {
            const short8 Bf = *reinterpret_cast<const short8*>(&s_w2f[((kt * 4 + nt) * 64 + lane) * 4]);
#pragma unroll
            for (int t = 0; t < 4; ++t)
                acc[t][nt] = __builtin_amdgcn_mfma_f32_16x16x32_bf16(A[t], Bf, acc[t][nt], 0, 0, 0);
        }
    }

    // ---- heads: feature-major f2 tile, b64 writes, u16 reads ----
    const float hbias = wsf[WS_HBIAS + m];
    float b2v[4];
#pragma unroll
    for (int nt = 0; nt < 4; ++nt) b2v[nt] = wsf[WS_B2V + nt * 16 + m];
    const short8 hB0 = *reinterpret_cast<const short8*>(ws + WS_HBF + lane * 4);
    const short8 hB1 = *reinterpret_cast<const short8*>(ws + WS_HBF + 256 + lane * 4);

    unsigned short* f2b = reinterpret_cast<unsigned short*>(&s_buf[wv][0]);
    f32x4 ha[4];

#pragma unroll
    for (int t = 0; t < 4; ++t) {
#pragma unroll
        for (int nt = 0; nt < 4; ++nt) {
            const float v0 = fmaxf(acc[t][nt][0] + b2v[nt], 0.f);
            const float v1 = fmaxf(acc[t][nt][1] + b2v[nt], 0.f);
            const float v2 = fmaxf(acc[t][nt][2] + b2v[nt], 0.f);
            const float v3 = fmaxf(acc[t][nt][3] + b2v[nt], 0.f);
            uint2 u;
            u.x = cvtpk(v0, v1);
            u.y = cvtpk(v2, v3);
            *reinterpret_cast<uint2*>(&f2b[(nt * 16 + m) * FS + q * 4]) = u;
        }

        short8 Afr[2];
#pragma unroll
        for (int kt2 = 0; kt2 < 2; ++kt2) {
            union { unsigned int u[4]; short8 s; } af;
#pragma unroll
            for (int jj = 0; jj < 4; ++jj) {
                const unsigned int lo = f2b[(kt2 * 32 + q * 8 + 2 * jj)     * FS + m];
                const unsigned int hi = f2b[(kt2 * 32 + q * 8 + 2 * jj + 1) * FS + m];
                af.u[jj] = lo | (hi << 16);
            }
            Afr[kt2] = af.s;
        }
        f32x4 h4 = {0, 0, 0, 0};
        h4 = __builtin_amdgcn_mfma_f32_16x16x32_bf16(Afr[0], hB0, h4, 0, 0, 0);
        h4 = __builtin_amdgcn_mfma_f32_16x16x32_bf16(Afr[1], hB1, h4, 0, 0, 0);
        ha[t] = h4;
    }

    // ---- xfer: redistribute 11 outs/point into per-wave LDS (f2 dead) ----
    float* xfer = reinterpret_cast<float*>(&s_buf[wv][0]);
    if (m < 11) {
#pragma unroll
        for (int t = 0; t < 4; ++t)
#pragma unroll
            for (int r = 0; r < 4; ++r)
                xfer[(t * 16 + q * 4 + r) * 11 + m] = ha[t][r] + hbias;
    }

    // ---- bc phase: lane i handles point pb0+i; stores ALL outputs ----
    float xv[11];
#pragma unroll
    for (int s = 0; s < 11; ++s) xv[s] = xfer[lane * 11 + s];

    const int n = pb0 + lane;
    const int b = n >> 16;
    const int h = (n >> 8) & 255;
    const int w = n & 255;

    *reinterpret_cast<float2*>(&out[OFF_OFFSET + 2 * n]) = make_float2(xv[0], xv[1]);
    *reinterpret_cast<float4*>(&out[OFF_SPAK + 4 * n]) =
        make_float4(xv[7], xv[8], xv[9], xv[10]);

    if (h >= 5 && h < 251 && w >= 5 && w < 251) {
        const int hh = h - 5, ww = w - 5;
        const int tc = ((b * CROPD) + hh) * CROPD + ww;

        const float off0 = xv[0], off1 = xv[1];
        *reinterpret_cast<float2*>(&out[OFF_OOFF + 2 * tc]) = make_float2(off0, off1);
#pragma unroll
        for (int s = 0; s < 5; ++s) out[OFF_SPEKC + 5 * tc + s] = xv[2 + s];

        // grid-sample setup (gathers issued early)
        const float gx = fmaf((float)w, 2.0f / 255.0f, -1.0f) + off0 * (1.0f / 128.0f);
        const float gy = fmaf((float)h, 2.0f / 255.0f, -1.0f) + off1 * (1.0f / 128.0f);
        const float px = (gx + 1.0f) * 0.5f * 255.0f;
        const float py = (gy + 1.0f) * 0.5f * 255.0f;
        const float x0f = floorf(px), y0f = floorf(py);
        const float wx1 = px - x0f,  wy1 = py - y0f;
        const int x0 = (int)x0f, y0 = (int)y0f;
        const int x1 = x0 + 1,  y1 = y0 + 1;
        const bool vx0 = (x0 >= 0) & (x0 < 256);
        const bool vx1 = (x1 >= 0) & (x1 < 256);
        const bool vy0 = (y0 >= 0) & (y0 < 256);
        const bool vy1 = (y1 >= 0) & (y1 < 256);
        const int cx0 = min(max(x0, 0), 255), cx1 = min(max(x1, 0), 255);
        const int cy0 = min(max(y0, 0), 255), cy1 = min(max(y1, 0), 255);
        const float w00 = (1.0f - wy1) * (1.0f - wx1) * (float)(vy0 & vx0);
        const float w01 = (1.0f - wy1) * wx1          * (float)(vy0 & vx1);
        const float w10 = wy1 * (1.0f - wx1)          * (float)(vy1 & vx0);
        const float w11 = wy1 * wx1                   * (float)(vy1 & vx1);
        const int i00 = cy0 * 256 + cx0;
        const int i01 = cy0 * 256 + cx1;
        const int i10 = cy1 * 256 + cx0;
        const int i11 = cy1 * 256 + cx1;
        const float* mb = msi + ((size_t)b * 4) * 65536;
        float m00[4], m01[4], m10[4], m11[4];
#pragma unroll
        for (int ch = 0; ch < 4; ++ch) {
            const float* mc = mb + ch * 65536;
            m00[ch] = mc[i00]; m01[ch] = mc[i01]; m10[ch] = mc[i10]; m11[ch] = mc[i11];
        }

        // conv: multiplicative fwd-diff in exp2 space + ALIGNED float4 rows.
        // Row base col 4w-8 (16B aligned, always in-bounds: w>=5 -> col>=12,
        // max col 4w+11 <= 1011). Taps qq=0..14 live at f[qq+2].
        const float a = xv[7], c = xv[9], d = xv[10];
        const float inv00 = a * a + c * c;
        const float inv01 = c * d;
        const float inv11 = d * d;
        const float c00 = -0.72134752f * inv00;
        const float c01 = -1.44269504f * inv01;
        const float c11 = -0.72134752f * inv11;
        const float* prow8 = pan + ((size_t)b << 20) + (size_t)(4 * h - 6) * 1024 + (4 * w - 8);

        const float s2 = __builtin_amdgcn_exp2f(2.0f * c11);
        float ksh  = 0.0f;                       // half-sum, excludes center
        float conv;
        {
            // row 7 (gp=0): center f[9], pair k: f[9-k] + f[9+k]
            union { float4 v[5]; float f[20]; } fr;
#pragma unroll
            for (int i = 0; i < 5; ++i)
                fr.v[i] = *reinterpret_cast<const float4*>(prow8 + 7 * 1024 + 4 * i);
            conv = fr.f[9];
            float kv = __builtin_amdgcn_exp2f(c11);
            float rr = __builtin_amdgcn_exp2f(3.0f * c11);
#pragma unroll
            for (int k = 1; k <= 7; ++k) {
                conv = fmaf(kv, fr.f[9 - k] + fr.f[9 + k], conv);
                ksh += kv;
                kv *= rr; rr *= s2;
            }
        }
#pragma unroll 1
        for (int p = 0; p < 7; ++p) {            // rows p & 14-p
            union { float4 v[5]; float f[20]; } fa, fc;
#pragma unroll
            for (int i = 0; i < 5; ++i) {
                fa.v[i] = *reinterpret_cast<const float4*>(prow8 + p * 1024 + 4 * i);
                fc.v[i] = *reinterpret_cast<const float4*>(prow8 + (14 - p) * 1024 + 4 * i);
            }
            const float gp = (float)(p - 7);
            const float cg = c01 * gp;
            float kv = __builtin_amdgcn_exp2f(fmaf(cg, -7.0f, fmaf(c00 * gp, gp, 49.0f * c11)));
            float rr = __builtin_amdgcn_exp2f(fmaf(-13.0f, c11, cg));
            // tap qq in row p pairs with tap 14-qq in row 14-p = fc.f[16-qq]
#pragma unroll
            for (int qq = 0; qq < 15; ++qq) {
                conv = fmaf(kv, fa.f[qq + 2] + fc.f[16 - qq], conv);
                ksh += kv;
                kv *= rr; rr *= s2;
            }
        }
        const float ksum = fmaf(2.0f, ksh, 1.0f);
        out[OFF_PREPAN + tc] = conv / ksum;

        // finish sample + pre_msi
        float pm = xv[6];
#pragma unroll
        for (int ch = 0; ch < 4; ++ch) {
            const float v = w00 * m00[ch] + w01 * m01[ch] + w10 * m10[ch] + w11 * m11[ch];
            out[OFF_OMSI + (((b * 4) + ch) * CROPD + hh) * CROPD + ww] = v;
            pm = fmaf(v, xv[2 + ch], pm);
        }
        out[OFF_PREMSI + tc] = pm;
    }
}

extern "C" void kernel_launch(void* const* d_in, const int* in_sizes, int n_in,
                              void* d_out, int out_size, void* d_ws, size_t ws_size,
                              hipStream_t stream)
{
    const float* msi    = (const float*)d_in[0];
    const float* pan    = (const float*)d_in[1];
    const float* coords = (const float*)d_in[2];
    const float* w1  = (const float*)d_in[3];
    const float* b1  = (const float*)d_in[4];
    const float* w2  = (const float*)d_in[5];
    const float* b2  = (const float*)d_in[6];
    const float* wo  = (const float*)d_in[7];
    const float* bo  = (const float*)d_in[8];
    const float* wse = (const float*)d_in[9];
    const float* bse = (const float*)d_in[10];
    const float* wsa = (const float*)d_in[11];
    const float* bsa = (const float*)d_in[12];
    float* out = (float*)d_out;
    unsigned int* ws = (unsigned int*)d_ws;

    prep_kernel<<<(WS_NDW + 255) / 256, 256, 0, stream>>>(
        w1, b1, w2, b2, wo, bo, wse, bse, wsa, bsa, ws);
    fused_kernel<<<1024, 256, 0, stream>>>(coords, ws, pan, msi, out);
}